// Round 12
// baseline (422.962 us; speedup 1.0000x reference)
//
#include <hip/hip_runtime.h>
#include <math.h>

#define KN 20000
#define KM 320000

typedef __attribute__((ext_vector_type(8))) short bf16x8;
typedef __attribute__((ext_vector_type(4))) float f32x4;

__device__ __forceinline__ ushort f2bf(float f){
  union{float f; unsigned u;} a; a.f=f;
  unsigned r = a.u + 0x7FFFu + ((a.u>>16)&1u);
  return (ushort)(r>>16);
}
__device__ __forceinline__ float bf2f(ushort u){
  union{unsigned u; float f;} a; a.u=((unsigned)u)<<16; return a.f;
}

// ---------------- helpers ----------------
__device__ __forceinline__ void blk_add2(double lp, double en, double* acc, double* sh){
#pragma unroll
  for (int o=32;o;o>>=1){ lp+=__shfl_xor(lp,o,64); en+=__shfl_xor(en,o,64); }
  int w=threadIdx.x>>6;
  if ((threadIdx.x&63)==0){ sh[2*w]=lp; sh[2*w+1]=en; }
  __syncthreads();
  if (threadIdx.x==0){
    double L=0,E=0; int nw=(blockDim.x+63)>>6;
    for (int i=0;i<nw;i++){L+=sh[2*i];E+=sh[2*i+1];}
    atomicAdd(&acc[0],L); atomicAdd(&acc[1],E);
  }
  __syncthreads();
}

// ---------------- consolidated prep: init + weight preps + x hi/lo split ----------------
__global__ __launch_bounds__(256) void k_prep_all(
    const float* __restrict__ x, ushort* __restrict__ x_hi, ushort* __restrict__ x_lo,
    const float* __restrict__ Wr1, ushort* __restrict__ Wrt_hi, ushort* __restrict__ Wrt_lo,
    double* __restrict__ w1d,
    const float* __restrict__ Wc1, ushort* __restrict__ W1t,
    const float* __restrict__ Wy1, ushort* __restrict__ W1yt,
    const float* __restrict__ Wy2, ushort* __restrict__ W2yt,
    int* __restrict__ deg,int* __restrict__ fill,int* __restrict__ keep,
    int* __restrict__ counters,double* __restrict__ acc){
  int i=blockIdx.x*256+threadIdx.x;
  if (i<KN*512/8){
    const float* s=x+(size_t)i*8;
    union{ushort u[8]; uint4 v;} oh, ol;
#pragma unroll
    for (int j=0;j<8;j++){
      float v=s[j];
      ushort h=f2bf(v);
      oh.u[j]=h;
      ol.u[j]=f2bf(v-bf2f(h));
    }
    *(uint4*)(x_hi+(size_t)i*8)=oh.v;
    *(uint4*)(x_lo+(size_t)i*8)=ol.v;
  }
  if (i<512*256){
    w1d[i]=(double)Wr1[i];
    int n=i&255, k=i>>8;
    float wv=Wr1[(size_t)k*256+n];
    ushort h=f2bf(wv);
    int kt=k>>5, kc=(k>>3)&3, j=k&7;
    size_t dst=(((size_t)kt*1024)+(size_t)kc*256+(size_t)n)*8+j;
    Wrt_hi[dst]=h;
    Wrt_lo[dst]=f2bf(wv-bf2f(h));
  }
  if (i<832*128){
    int n=i&127, k=i>>7;
    W1t[(size_t)n*832+k]=f2bf(Wc1[(size_t)k*128+n]);
  }
  if (i<384*128){
    int n=i&127, k=i>>7;
    W1yt[(size_t)n*384+k]=f2bf(Wy1[(size_t)k*128+n]);
  }
  if (i<128*256){
    int n=i&255, k=i>>8;
    W2yt[(size_t)n*128+k]=f2bf(Wy2[(size_t)k*256+n]);
  }
  if (i<KN){ deg[i]=0; fill[i]=0; keep[i]=0; }
  if (i<8) counters[i]=0;
  if (i<2) acc[i]=0.0;
}

// ---------------- mega1: rmlp + hx GEMM + ymlp-compute, type-interleaved by bid%5 ----------------
// R10 structure/math (staged hi+lo dbuf, bit-identical outputs). Only change: block-type map.
// rmlp on bid%5==0 (exactly 313 of 1563) so long-pole rmlp blocks spread across all CUs and
// short hx/ymlp blocks backfill their barrier stalls everywhere.
#define RFLAG_TAU 3e-4f
#define YEXTP 261
__global__ __launch_bounds__(512) void k_mega1(const float* __restrict__ x,
    const ushort* __restrict__ x_hi,const ushort* __restrict__ x_lo,
    const ushort* __restrict__ Wrt_hi,const ushort* __restrict__ Wrt_lo,
    const double* __restrict__ w1d,
    const float* __restrict__ b1,const float* __restrict__ g1,
    const float* __restrict__ bt1,const float* __restrict__ W2,const float* __restrict__ b2,
    const float* __restrict__ u_r, float* __restrict__ pr, int* __restrict__ choose,
    const ushort* __restrict__ W1t, float* __restrict__ hxP,
    const ushort* __restrict__ W1yt,const float* __restrict__ b1y,const float* __restrict__ g1y,
    const float* __restrict__ bt1y,const ushort* __restrict__ W2yt,const float* __restrict__ b2y,
    float* __restrict__ y1_f,float* __restrict__ y2_f,
    float* __restrict__ yagg_f,ushort* __restrict__ yagg_bf,
    int RB,int HXB){
  __shared__ __align__(16) ushort Bl[2][2][8192];   // 64 KB (rmlp dbuf; ymlp aliases)
  __shared__ float psum[64][2], pvar[64][2], pdot[64][2];
  __shared__ int flagsh[64];
  __shared__ double dsh[256];
  int t=threadIdx.x;
  int w=t>>6, l=t&63;
  int lr=l&15, lk=l>>4;
  // ---- block-type interleave map ----
  int bid=blockIdx.x;
  int typ, idx;
  if ((bid%5)==0){ typ=0; idx=bid/5; }
  else {
    int rank=bid-(bid/5)-1;
    if (rank<HXB){ typ=1; idx=rank; }
    else { typ=2; idx=rank-HXB; }
  }
  if (typ==2){
    // ---- ymlp-compute: 2 groups of 16 rows ----
    int b=idx;
    int sub=t>>8, tt=t&255;
    char* gbase=(char*)Bl + sub*25600;
    float*  hf  =(float*)gbase;
    float*  yext=(float*)gbase;
    ushort* hb  =(ushort*)(gbase+16896);
    int wy=tt>>6, ly=tt&63;
    int lry=ly&15, lky=ly>>4;
    int md=wy&1, kh=wy>>1;
    int row0=(b*2+sub)*16;
    const ushort* xr=x_hi+(size_t)(row0+lry)*512;
    f32x4 acc1[8];
#pragma unroll
    for (int c=0;c<8;c++) acc1[c]=(f32x4){0,0,0,0};
#pragma unroll
    for (int kt=0;kt<6;kt++){
      int k0=kh*192+kt*32+lky*8;
      int ks=(md && k0>=256)? k0+128 : k0;
      bf16x8 a=*(const bf16x8*)(xr+ks);
#pragma unroll
      for (int c=0;c<8;c++){
        bf16x8 b_=*(const bf16x8*)(W1yt+(size_t)(c*16+lry)*384+k0);
        acc1[c]=__builtin_amdgcn_mfma_f32_16x16x32_bf16(a,b_,acc1[c],0,0,0);
      }
    }
    if (kh==0){
#pragma unroll
      for (int i=0;i<4;i++){
        int row=lky*4+i;
#pragma unroll
        for (int c=0;c<8;c++) hf[((size_t)md*16+row)*132+c*16+lry]=acc1[c][i];
      }
    }
    __syncthreads();   // B1
    if (kh==1){
      float b1v[8],g1v[8],btv[8];
#pragma unroll
      for (int c=0;c<8;c++){ int col=c*16+lry; b1v[c]=b1y[col]; g1v[c]=g1y[col]; btv[c]=bt1y[col]; }
#pragma unroll
      for (int i=0;i<4;i++){
        int row=lky*4+i;
        float hv[8]; float s=0.f;
#pragma unroll
        for (int c=0;c<8;c++){ hv[c]=acc1[c][i]+hf[((size_t)md*16+row)*132+c*16+lry]+b1v[c]; s+=hv[c]; }
#pragma unroll
        for (int o=8;o;o>>=1) s+=__shfl_xor(s,o,64);
        float mu=s*(1.0f/128.0f);
        float v=0.f;
#pragma unroll
        for (int c=0;c<8;c++){ float d=hv[c]-mu; v+=d*d; }
#pragma unroll
        for (int o=8;o;o>>=1) v+=__shfl_xor(v,o,64);
        float rs=1.0f/sqrtf(v*(1.0f/128.0f)+1e-5f);
        ushort* hrow=hb+((size_t)md*16+row)*136;
#pragma unroll
        for (int c=0;c<8;c++){
          float hn=(hv[c]-mu)*rs*g1v[c]+btv[c];
          hn=hn>=0.f?hn:0.05f*hn;
          hrow[c*16+lry]=f2bf(hn);
        }
      }
    }
    __syncthreads();   // B2
    f32x4 acc2[8];
#pragma unroll
    for (int c=0;c<8;c++) acc2[c]=(f32x4){0,0,0,0};
    const ushort* ha=hb+((size_t)md*16+lry)*136;
#pragma unroll
    for (int kt=0;kt<4;kt++){
      bf16x8 a=*(const bf16x8*)(ha+kt*32+lky*8);
#pragma unroll
      for (int c=0;c<8;c++){
        bf16x8 b_=*(const bf16x8*)(W2yt+(size_t)(kh*128+c*16+lry)*128+kt*32+lky*8);
        acc2[c]=__builtin_amdgcn_mfma_f32_16x16x32_bf16(a,b_,acc2[c],0,0,0);
      }
    }
    float b2v[8];
#pragma unroll
    for (int c=0;c<8;c++) b2v[c]=b2y[kh*128+c*16+lry];
    if (md==0){
#pragma unroll
      for (int i=0;i<4;i++){
        int row=lky*4+i;
#pragma unroll
        for (int c=0;c<8;c++) yext[(size_t)row*YEXTP+kh*128+c*16+lry]=acc2[c][i]+b2v[c];
      }
    }
    __syncthreads();   // B3
    if (md==0){
#pragma unroll
      for (int i=0;i<4;i++){
        int row=lky*4+i, n=row0+row;
        float* orow=y1_f+(size_t)n*256+kh*128;
#pragma unroll
        for (int c=0;c<8;c++) orow[c*16+lry]=acc2[c][i]+b2v[c];
      }
    } else {
#pragma unroll
      for (int i=0;i<4;i++){
        int row=lky*4+i, n=row0+row;
        size_t base=(size_t)n*256+kh*128;
#pragma unroll
        for (int c=0;c<8;c++){
          int colk=c*16+lry;
          float v2=acc2[c][i]+b2v[c];
          float v1=yext[(size_t)row*YEXTP+kh*128+colk];
          float ga=v1+v2; ga=ga>=0.f?ga:0.05f*ga;
          yagg_f[base+colk]=ga;
          yagg_bf[base+colk]=f2bf(ga);
          y2_f[base+colk]=v2;
        }
      }
    }
    return;
  }
  if (typ==1){
    // ---- hx: rows idx*32 + (w>>2)*16, cols (w&3)*32 .. +31 ----
    int b2=idx;
    int rh=w>>2, cw=w&3;
    int row0=b2*32+rh*16;
    const ushort* ar=x_hi+(size_t)(row0+lr)*512;
    f32x4 acc3[2];
#pragma unroll
    for (int c=0;c<2;c++) acc3[c]=(f32x4){0,0,0,0};
#pragma unroll
    for (int kt=0;kt<16;kt++){
      bf16x8 a=*(const bf16x8*)(ar+320+kt*32+lk*8);
#pragma unroll
      for (int c=0;c<2;c++){
        bf16x8 b=*(const bf16x8*)(W1t+(size_t)(cw*32+c*16+lr)*832+320+kt*32+lk*8);
        acc3[c]=__builtin_amdgcn_mfma_f32_16x16x32_bf16(a,b,acc3[c],0,0,0);
      }
    }
#pragma unroll
    for (int i=0;i<4;i++){
      int n=row0+lk*4+i;
      float2 v; v.x=acc3[0][i]; v.y=acc3[1][i];
      *(float2*)(hxP+(size_t)n*128+lr*8+cw*2)=v;
    }
    return;
  }
  // ---- rmlp (exact R4/R10 math) ----
  int rg=w>>1, ch=w&1;
  int row0=idx*64;
  if (t<64) flagsh[t]=0;
  int q0=t*2, q1=t*2+1;
  f32x4 acc[8];
#pragma unroll
  for (int c=0;c<8;c++) acc[c]=(f32x4){0,0,0,0};
  int rowA=row0+rg*16+lr; if (rowA>=KN) rowA=KN-1;
  const ushort* ah=x_hi+(size_t)rowA*512;
  const ushort* al=x_lo+(size_t)rowA*512;
  bf16x8 nh0=*(const bf16x8*)(Wrt_hi+q0*8);
  bf16x8 nh1=*(const bf16x8*)(Wrt_hi+q1*8);
  bf16x8 nl0=*(const bf16x8*)(Wrt_lo+q0*8);
  bf16x8 nl1=*(const bf16x8*)(Wrt_lo+q1*8);
  *(bf16x8*)&Bl[0][0][q0*8]=nh0; *(bf16x8*)&Bl[0][0][q1*8]=nh1;
  *(bf16x8*)&Bl[0][1][q0*8]=nl0; *(bf16x8*)&Bl[0][1][q1*8]=nl1;
  nh0=*(const bf16x8*)(Wrt_hi+8192+q0*8);
  nh1=*(const bf16x8*)(Wrt_hi+8192+q1*8);
  nl0=*(const bf16x8*)(Wrt_lo+8192+q0*8);
  nl1=*(const bf16x8*)(Wrt_lo+8192+q1*8);
  bf16x8 a_h0=*(const bf16x8*)(ah+0*32+lk*8), a_l0=*(const bf16x8*)(al+0*32+lk*8);
  bf16x8 a_h1=*(const bf16x8*)(ah+1*32+lk*8), a_l1=*(const bf16x8*)(al+1*32+lk*8);
  bf16x8 a_h2=*(const bf16x8*)(ah+2*32+lk*8), a_l2=*(const bf16x8*)(al+2*32+lk*8);
  bf16x8 a_h3=*(const bf16x8*)(ah+3*32+lk*8), a_l3=*(const bf16x8*)(al+3*32+lk*8);
  __syncthreads();
#define RBODY(KT,AH,AL) { \
    const int cur_=(KT)&1, nxt_=cur_^1; \
    if ((KT)<15){ \
      *(bf16x8*)&Bl[nxt_][0][q0*8]=nh0; *(bf16x8*)&Bl[nxt_][0][q1*8]=nh1; \
      *(bf16x8*)&Bl[nxt_][1][q0*8]=nl0; *(bf16x8*)&Bl[nxt_][1][q1*8]=nl1; \
      if ((KT)<14){ \
        size_t so_=(size_t)((KT)+2)*8192; \
        nh0=*(const bf16x8*)(Wrt_hi+so_+q0*8); nh1=*(const bf16x8*)(Wrt_hi+so_+q1*8); \
        nl0=*(const bf16x8*)(Wrt_lo+so_+q0*8); nl1=*(const bf16x8*)(Wrt_lo+so_+q1*8); \
      } \
    } \
    bf16x8 uh_=AH, ul_=AL; \
    if ((KT)<12){ \
      int ko_=((KT)+4)*32+lk*8; \
      AH=*(const bf16x8*)(ah+ko_); \
      AL=*(const bf16x8*)(al+ko_); \
    } \
    _Pragma("unroll") \
    for (int c=0;c<8;c++){ \
      int col_=ch*128+c*16+lr; \
      bf16x8 vh_=*(const bf16x8*)&Bl[cur_][0][((lk<<8)+col_)*8]; \
      bf16x8 vl_=*(const bf16x8*)&Bl[cur_][1][((lk<<8)+col_)*8]; \
      acc[c]=__builtin_amdgcn_mfma_f32_16x16x32_bf16(uh_,vh_,acc[c],0,0,0); \
      acc[c]=__builtin_amdgcn_mfma_f32_16x16x32_bf16(uh_,vl_,acc[c],0,0,0); \
      acc[c]=__builtin_amdgcn_mfma_f32_16x16x32_bf16(ul_,vh_,acc[c],0,0,0); \
    } \
    __syncthreads(); \
  }
  RBODY(0,a_h0,a_l0)  RBODY(1,a_h1,a_l1)  RBODY(2,a_h2,a_l2)  RBODY(3,a_h3,a_l3)
  RBODY(4,a_h0,a_l0)  RBODY(5,a_h1,a_l1)  RBODY(6,a_h2,a_l2)  RBODY(7,a_h3,a_l3)
  RBODY(8,a_h0,a_l0)  RBODY(9,a_h1,a_l1)  RBODY(10,a_h2,a_l2) RBODY(11,a_h3,a_l3)
  RBODY(12,a_h0,a_l0) RBODY(13,a_h1,a_l1) RBODY(14,a_h2,a_l2) RBODY(15,a_h3,a_l3)
#undef RBODY
  float b1v[8],g1v[8],btv[8],w2v[8];
#pragma unroll
  for (int c=0;c<8;c++){
    int col=ch*128+c*16+lr;
    b1v[c]=b1[col]; g1v[c]=g1[col]; btv[c]=bt1[col]; w2v[c]=W2[col];
  }
  float hv[4][8];
#pragma unroll
  for (int i=0;i<4;i++){
    float s=0.f;
#pragma unroll
    for (int c=0;c<8;c++){ hv[i][c]=acc[c][i]+b1v[c]; s+=hv[i][c]; }
#pragma unroll
    for (int o=8;o;o>>=1) s+=__shfl_xor(s,o,64);
    if (lr==0) psum[rg*16+lk*4+i][ch]=s;
  }
  __syncthreads();
  float mu_[4];
#pragma unroll
  for (int i=0;i<4;i++){
    int r=rg*16+lk*4+i;
    mu_[i]=(psum[r][0]+psum[r][1])*(1.0f/256.0f);
    float v=0.f;
#pragma unroll
    for (int c=0;c<8;c++){ float d=hv[i][c]-mu_[i]; v+=d*d; }
#pragma unroll
    for (int o=8;o;o>>=1) v+=__shfl_xor(v,o,64);
    if (lr==0) pvar[r][ch]=v;
  }
  __syncthreads();
#pragma unroll
  for (int i=0;i<4;i++){
    int r=rg*16+lk*4+i;
    float rs=1.0f/sqrtf((pvar[r][0]+pvar[r][1])*(1.0f/256.0f)+1e-5f);
    float dot=0.f;
#pragma unroll
    for (int c=0;c<8;c++){
      float hn=(hv[i][c]-mu_[i])*rs*g1v[c]+btv[c];
      hn=hn>=0.f?hn:0.05f*hn;
      dot=fmaf(hn,w2v[c],dot);
    }
#pragma unroll
    for (int o=8;o;o>>=1) dot+=__shfl_xor(dot,o,64);
    if (lr==0) pdot[r][ch]=dot;
  }
  __syncthreads();
  if (t<64){
    int n=row0+t;
    if (n<KN){
      float o2=pdot[t][0]+pdot[t][1]+b2[0];
      float pf=1.0f/(1.0f+expf(-o2));
      float u=u_r[n];
      pr[n]=pf;
      choose[n]=(u<pf)?1:0;
      if (fabsf(pf-u)<RFLAG_TAU) flagsh[t]=1;
    }
  }
  __syncthreads();
  for (int r=0;r<64;r++){
    if (!flagsh[r]) continue;
    int n=row0+r;
    if (t<256){
      double ha=(double)b1[t];
      const float* xr=x+(size_t)n*512;
      for (int k=0;k<512;k++) ha=fma((double)xr[k],w1d[(size_t)k*256+t],ha);
      dsh[t]=ha;
    }
    __syncthreads();
    if (t<64){
      double s=0;
      for (int j=t;j<256;j+=64) s+=dsh[j];
#pragma unroll
      for (int o=32;o;o>>=1) s+=__shfl_xor(s,o,64);
      double mu=s*(1.0/256.0);
      double v=0;
      for (int j=t;j<256;j+=64){ double d=dsh[j]-mu; v+=d*d; }
#pragma unroll
      for (int o=32;o;o>>=1) v+=__shfl_xor(v,o,64);
      double rs=1.0/sqrt(v*(1.0/256.0)+1e-5);
      double dot=0;
      for (int j=t;j<256;j+=64){
        double hn=(dsh[j]-mu)*rs*(double)g1[j]+(double)bt1[j];
        hn = hn>=0.0? hn : 0.05*hn;
        dot=fma(hn,(double)W2[j],dot);
      }
#pragma unroll
      for (int o=32;o;o>>=1) dot+=__shfl_xor(dot,o,64);
      if (t==0){
        double p=1.0/(1.0+exp(-(dot+(double)b2[0])));
        float pf=(float)p;
        pr[n]=pf;
        choose[n]=(u_r[n]<pf)?1:0;
      }
    }
    __syncthreads();
  }
}

// ---------------- single-block scan (wave-shuffle) ----------------
__global__ __launch_bounds__(1024) void k_scan_choose(const int* __restrict__ choose,int* __restrict__ excl,
                                                      int* __restrict__ iu,int* __restrict__ counters){
  __shared__ int wsum[16], woff[16];
  const int CH=(KN+1023)/1024;
  int t=threadIdx.x, lane=t&63, wid=t>>6;
  int base=t*CH;
  int s=0;
  for (int i=0;i<CH;i++){int idx=base+i; if (idx<KN) s+=choose[idx];}
  int inc=s;
  for (int o=1;o<64;o<<=1){ int v=__shfl_up(inc,o,64); if (lane>=o) inc+=v; }
  if (lane==63) wsum[wid]=inc;
  __syncthreads();
  if (t==0){ int r=0; for (int i=0;i<16;i++){ woff[i]=r; r+=wsum[i]; } counters[2]=r; }
  __syncthreads();
  int ex=woff[wid]+inc-s;
  for (int i=0;i<CH;i++){
    int idx=base+i;
    if (idx<KN){ int c=choose[idx]; excl[idx]=ex; if (c) iu[ex]=idx; ex+=c; }
  }
}

// ---------------- mega2: hy GEMM + ia MLP + y1/y2 scatter + node_term ----------------
__global__ __launch_bounds__(256) void k_mega2(const float* __restrict__ yagg_f,
    const ushort* __restrict__ yagg_bf,const ushort* __restrict__ W1t,float* __restrict__ hyP,
    const int* __restrict__ iu,const float* __restrict__ u_ia,
    const float* __restrict__ W1,const float* __restrict__ b1,const float* __restrict__ g1,
    const float* __restrict__ bt1,const float* __restrict__ W2,const float* __restrict__ b2,
    float* __restrict__ p_ia,int* __restrict__ vc,int* __restrict__ keep,double* __restrict__ acc,
    const float* __restrict__ y1_f,const float* __restrict__ y2_f,
    const int* __restrict__ choose,const int* __restrict__ excl,
    float* __restrict__ out,const float* __restrict__ pr,
    int cnt,int HB,int IAB,int SCB){
  __shared__ float insh[16][256];
  __shared__ float hsh[16][128];
  __shared__ double sh[8];
  int t=threadIdx.x;
  int w=t>>6, l=t&63;
  int lr=l&15, lk=l>>4;
  if ((int)blockIdx.x<HB){
    int rh=w>>1, cq=w&1;
    int row0=blockIdx.x*32+rh*16;
    const ushort* ar=yagg_bf+(size_t)(row0+lr)*256+lk*8;
    f32x4 acc4[4];
#pragma unroll
    for (int c=0;c<4;c++) acc4[c]=(f32x4){0,0,0,0};
#pragma unroll
    for (int kt=0;kt<8;kt++){
      bf16x8 a=*(const bf16x8*)(ar+kt*32);
#pragma unroll
      for (int c=0;c<4;c++){
        bf16x8 b=*(const bf16x8*)(W1t+(size_t)(cq*64+c*16+lr)*832+kt*32+lk*8);
        acc4[c]=__builtin_amdgcn_mfma_f32_16x16x32_bf16(a,b,acc4[c],0,0,0);
      }
    }
#pragma unroll
    for (int i=0;i<4;i++){
      int n=row0+lk*4+i;
      float4 v; v.x=acc4[0][i]; v.y=acc4[1][i]; v.z=acc4[2][i]; v.w=acc4[3][i];
      *(float4*)(hyP+(size_t)n*128+lr*8+cq*4)=v;
    }
    return;
  }
  if ((int)blockIdx.x<HB+IAB){
    int row0=(blockIdx.x-HB)*16;
    for (int i=t;i<16*256;i+=256){
      int r=i>>8,k=i&255;
      int row=row0+r;
      if (row<cnt){
        unsigned n=(unsigned)iu[row];
        if (n<KN) insh[r][k]=yagg_f[(size_t)n*256+k];
        else insh[r][k]=0.f;
      }
    }
    __syncthreads();
    int h=t>>7, tt=t&127;
    float accv[8]; float bb=b1[tt];
#pragma unroll
    for (int r=0;r<8;r++) accv[r]=bb;
    for (int k=0;k<256;k+=4){
      float w0=W1[(k+0)*128+tt],w1=W1[(k+1)*128+tt],w2=W1[(k+2)*128+tt],w3=W1[(k+3)*128+tt];
#pragma unroll
      for (int r=0;r<8;r++){
        float4 f=*(const float4*)&insh[h*8+r][k];
        accv[r]=fmaf(f.x,w0,accv[r]); accv[r]=fmaf(f.y,w1,accv[r]); accv[r]=fmaf(f.z,w2,accv[r]); accv[r]=fmaf(f.w,w3,accv[r]);
      }
    }
#pragma unroll
    for (int r=0;r<8;r++) hsh[h*8+r][tt]=accv[r];
    __syncthreads();
    int g=t>>4, tl=t&15;
    float hv[8];
#pragma unroll
    for (int j=0;j<8;j++) hv[j]=hsh[g][tl+16*j];
    float s=0;
#pragma unroll
    for (int j=0;j<8;j++) s+=hv[j];
#pragma unroll
    for (int o=8;o;o>>=1) s+=__shfl_xor(s,o,64);
    float mu=s*(1.0f/128.0f);
    float v=0;
#pragma unroll
    for (int j=0;j<8;j++){float d=hv[j]-mu; v+=d*d;}
#pragma unroll
    for (int o=8;o;o>>=1) v+=__shfl_xor(v,o,64);
    float rs=1.0f/sqrtf(v*(1.0f/128.0f)+1e-5f);
    float dot=0;
#pragma unroll
    for (int j=0;j<8;j++){
      int idx=tl+16*j;
      float hn=(hv[j]-mu)*rs*g1[idx]+bt1[idx];
      hn=hn>=0.f?hn:0.05f*hn;
      dot=fmaf(hn,W2[idx],dot);
    }
#pragma unroll
    for (int o=8;o;o>>=1) dot+=__shfl_xor(dot,o,64);
    double lp=0,en=0;
    if (tl==0){
      int row=row0+g;
      if (row<cnt){
        unsigned n=(unsigned)iu[row];
        if (n<KN){
          float o=dot+b2[0];
          double p=1.0/(1.0+exp(-(double)o));
          float pf=(float)p;
          p_ia[row]=pf;
          int vv=(u_ia[n]<pf)?1:0;
          vc[row]=vv;
          if(!vv) keep[n]=1;
          lp = vv? log((double)pf+1e-9) : log(1.0-(double)pf+1e-9);
          double ps=fmin(fmax((double)pf,1e-9),1.0-1e-9);
          en = -(ps*log(ps)+(1.0-ps)*log(1.0-ps));
        }
      }
    }
    blk_add2(lp,en,acc,sh);
    return;
  }
  if ((int)blockIdx.x<HB+IAB+SCB){
    int b=blockIdx.x-HB-IAB;
    int r0=b*32;
    for (int r=0;r<32;r++){
      int n=r0+r;
      if (n>=KN) break;
      int cch=choose[n], ex=excl[n];
      int r1 = cch? (KN-cnt)+ex : n-ex;
      if (r1>=0 && r1<KN+cnt) out[(size_t)r1*256+t]=y1_f[(size_t)n*256+t];
      if (cch){ int r2=KN+ex; if (r2<KN+cnt) out[(size_t)r2*256+t]=y2_f[(size_t)n*256+t]; }
    }
    return;
  }
  {
    int i=(blockIdx.x-HB-IAB-SCB)*256+t;
    double lp=0,en=0;
    if (i<KN){
      double p=(double)pr[i];
      lp = choose[i]? log(p+1e-9) : log(1.0-p+1e-9);
      double ps=fmin(fmax(p,1e-9),1.0-1e-9);
      en = -(ps*log(ps)+(1.0-ps)*log(1.0-ps));
    }
    blk_add2(lp,en,acc,(double*)insh);
  }
}

// ---------------- adjacency build ----------------
__global__ void k_count(const int* __restrict__ ei,const int* __restrict__ keep,int* __restrict__ deg){
  int e=blockIdx.x*256+threadIdx.x;
  if (e<KM){
    int s=ei[e], d=ei[KM+e];
    if (keep[s]) atomicAdd(&deg[s],1);
    if (keep[d]) atomicAdd(&deg[d],1);
  }
}

__global__ __launch_bounds__(1024) void k_scan_deg(const int* __restrict__ deg,int* __restrict__ boff,
                                                   int* __restrict__ nodeseg,int* __restrict__ counters){
  __shared__ int wsum[16], woff[16];
  const int CH=(KN+1023)/1024;
  int t=threadIdx.x, lane=t&63, wid=t>>6;
  int base=t*CH;
  int s=0, sc=0;
  for (int i=0;i<CH;i++){int idx=base+i; if(idx<KN){ int d=deg[idx]; s+=d; sc+=(d>0)?1:0; }}
  int inc=s;
  for (int o=1;o<64;o<<=1){ int v=__shfl_up(inc,o,64); if (lane>=o) inc+=v; }
  if (lane==63) wsum[wid]=inc;
  __syncthreads();
  if (t==0){ int r=0; for (int i=0;i<16;i++){ woff[i]=r; r+=wsum[i]; } boff[KN]=r; counters[0]=r; }
  __syncthreads();
  int ex=woff[wid]+inc-s;
  for (int i=0;i<CH;i++){int idx=base+i; if(idx<KN){ boff[idx]=ex; ex+=deg[idx]; }}
  __syncthreads();
  int inc2=sc;
  for (int o=1;o<64;o<<=1){ int v=__shfl_up(inc2,o,64); if (lane>=o) inc2+=v; }
  if (lane==63) wsum[wid]=inc2;
  __syncthreads();
  if (t==0){ int r=0; for (int i=0;i<16;i++){ woff[i]=r; r+=wsum[i]; } counters[1]=r; }
  __syncthreads();
  int ex2=woff[wid]+inc2-sc;
  for (int i=0;i<CH;i++){int idx=base+i; if(idx<KN && deg[idx]>0){ nodeseg[ex2]=idx; ex2++; }}
}

// key = nb*2 + half -> replicates stable lexsort tie-break
__global__ void k_fill(const int* __restrict__ ei,const int* __restrict__ keep,const int* __restrict__ boff,
                       int* __restrict__ fill,int* __restrict__ parA,int* __restrict__ keyA,int* __restrict__ ekA){
  int e=blockIdx.x*256+threadIdx.x;
  if (e<KM){
    int s=ei[e], d=ei[KM+e];
    if (keep[s]){ int pos=boff[s]+atomicAdd(&fill[s],1); parA[pos]=s; keyA[pos]=d*2;   ekA[pos]=e; }
    if (keep[d]){ int pos=boff[d]+atomicAdd(&fill[d],1); parA[pos]=d; keyA[pos]=s*2+1; ekA[pos]=e; }
  }
}

__global__ void k_rank(const int* __restrict__ parA,const int* __restrict__ keyA,const int* __restrict__ ekA,
                       const int* __restrict__ boff,const int* __restrict__ counters,
                       int* __restrict__ parS,int* __restrict__ nbS,int* __restrict__ ekS){
  int i=blockIdx.x*256+threadIdx.x;
  int Pn=counters[0];
  if (i<Pn){
    int par=parA[i], key=keyA[i];
    int lo=boff[par], hi=boff[par+1];
    int rank=0;
    for (int j=lo;j<hi;j++) rank += (keyA[j]<key)?1:0;
    int pos=lo+rank;
    parS[pos]=par; nbS[pos]=key>>1; ekS[pos]=ekA[i];
  }
}

// ---------------- c scores v6: no LDS, no barriers; ea converted inline ----------------
__global__ __launch_bounds__(256) void k_cscore_v6(
    const float* __restrict__ ea,const float* __restrict__ hyP,const float* __restrict__ hxP,
    const int* __restrict__ parS,const int* __restrict__ nbS,const int* __restrict__ ekS,
    const int* __restrict__ counters,
    const ushort* __restrict__ W1t,const float* __restrict__ b1,const float* __restrict__ g1,
    const float* __restrict__ bt1,const float* __restrict__ W2,const float* __restrict__ b2,
    float* __restrict__ scores){
  int Pn=counters[0];
  if (Pn<=0) return;
  int t=threadIdx.x;
  int w=t>>6, l=t&63;
  int lr=l&15, lk=l>>4;
  float b2s=b2[0];
  float b1v[8],g1v[8],btv[8],w2v[8];
#pragma unroll
  for (int c=0;c<8;c++){
    int col=c*16+lr;
    b1v[c]=b1[col]; g1v[c]=g1[col]; btv[c]=bt1[col]; w2v[c]=W2[col];
  }
  int ngrp=(Pn+63)>>6;
  for (int g=blockIdx.x; g<ngrp; g+=gridDim.x){
    int p0=g*64+w*16;
    float hs[4][8];
#pragma unroll
    for (int i=0;i<4;i++){
      int p=p0+lk*4+i; int pc=p<Pn?p:Pn-1;
      const float* hyp=hyP+(size_t)parS[pc]*128+lr*8;
      const float* hxp=hxP+(size_t)nbS[pc]*128+lr*8;
      float4 ya=*(const float4*)hyp, yb=*(const float4*)(hyp+4);
      float4 xa=*(const float4*)hxp, xb=*(const float4*)(hxp+4);
      hs[i][0]=ya.x+xa.x; hs[i][1]=ya.y+xa.y; hs[i][2]=ya.z+xa.z; hs[i][3]=ya.w+xa.w;
      hs[i][4]=yb.x+xb.x; hs[i][5]=yb.y+xb.y; hs[i][6]=yb.z+xb.z; hs[i][7]=yb.w+xb.w;
    }
    int pA=p0+lr; int ca=pA<Pn?pA:Pn-1;
    const float* eaA=ea+(size_t)ekS[ca]*64;
    f32x4 acc[8];
#pragma unroll
    for (int c=0;c<8;c++) acc[c]=(f32x4){0,0,0,0};
#pragma unroll
    for (int kt=0;kt<2;kt++){
      float4 fa=*(const float4*)(eaA+kt*32+lk*8);
      float4 fb=*(const float4*)(eaA+kt*32+lk*8+4);
      union{ushort u[8]; bf16x8 v;} A;
      A.u[0]=f2bf(fa.x); A.u[1]=f2bf(fa.y); A.u[2]=f2bf(fa.z); A.u[3]=f2bf(fa.w);
      A.u[4]=f2bf(fb.x); A.u[5]=f2bf(fb.y); A.u[6]=f2bf(fb.z); A.u[7]=f2bf(fb.w);
      bf16x8 a=A.v;
#pragma unroll
      for (int c=0;c<8;c++){
        bf16x8 b=*(const bf16x8*)(W1t+(size_t)(c*16+lr)*832+256+kt*32+lk*8);
        acc[c]=__builtin_amdgcn_mfma_f32_16x16x32_bf16(a,b,acc[c],0,0,0);
      }
    }
#pragma unroll
    for (int i=0;i<4;i++){
      float hv[8]; float s=0.f;
#pragma unroll
      for (int c=0;c<8;c++){ hv[c]=acc[c][i]+hs[i][c]+b1v[c]; s+=hv[c]; }
#pragma unroll
      for (int o=8;o;o>>=1) s+=__shfl_xor(s,o,64);
      float mu=s*(1.0f/128.0f);
      float v=0.f;
#pragma unroll
      for (int c=0;c<8;c++){ float d=hv[c]-mu; v+=d*d; }
#pragma unroll
      for (int o=8;o;o>>=1) v+=__shfl_xor(v,o,64);
      float rs=1.0f/sqrtf(v*(1.0f/128.0f)+1e-5f);
      float dot=0.f;
#pragma unroll
      for (int c=0;c<8;c++){
        float hn=(hv[c]-mu)*rs*g1v[c]+btv[c];
        hn=hn>=0.f?hn:0.05f*hn;
        dot=fmaf(hn,w2v[c],dot);
      }
#pragma unroll
      for (int o=8;o;o>>=1) dot+=__shfl_xor(dot,o,64);
      if (lr==0){
        int prow=p0+lk*4+i;
        if (prow<Pn) scores[prow]=dot+b2s;
      }
    }
  }
}

// ---------------- per-segment softmax, pick, logP/ent ----------------
__global__ __launch_bounds__(256) void k_segment(const float* __restrict__ scores,const int* __restrict__ boff,
    const int* __restrict__ nodeseg,const int* __restrict__ counters,const float* __restrict__ u_pick,
    double* __restrict__ acc){
  __shared__ double sh[8];
  int nseg=counters[1];
  int s=blockIdx.x*256+threadIdx.x;
  double lp=0,en=0;
  if (s<nseg){
    int n=nodeseg[s];
    int lo=boff[n],hi=boff[n+1];
    float mx=-1e30f;
    for (int p=lo;p<hi;p++) mx=fmaxf(mx,scores[p]);
    float den=0;
    for (int p=lo;p<hi;p++) den+=expf(scores[p]-mx);
    double u=(double)u_pick[n];
    double cum=0; float ppick=-1.f; float plast=0.f;
    for (int p=lo;p<hi;p++){
      float e=expf(scores[p]-mx);
      float prob=e/den;
      double pc=fmax((double)prob,1e-9);
      en -= pc*log(pc);
      plast=prob;
      if (ppick<0.f){ cum+=(double)prob; if (cum>u) ppick=prob; }
    }
    if (ppick<0.f) ppick=plast;
    lp=log(fmax((double)ppick,1e-9));
  }
  blk_add2(lp,en,acc,sh);
}

__global__ void k_final(const double* __restrict__ acc,float* __restrict__ out,int cnt){
  if (threadIdx.x==0 && blockIdx.x==0){
    size_t base=(size_t)(KN+cnt)*256;
    out[base]=(float)acc[0];
    out[base+1]=(float)acc[1];
  }
}

// ---------------- host ----------------
extern "C" void kernel_launch(void* const* d_in,const int* in_sizes,int n_in,
                              void* d_out,int out_size,void* d_ws,size_t ws_size,
                              hipStream_t stream){
  const float* x     =(const float*)d_in[0];
  const int*   ei    =(const int*)  d_in[1];
  const float* ea    =(const float*)d_in[2];
  const float* u_r   =(const float*)d_in[3];
  const float* u_ia  =(const float*)d_in[4];
  const float* u_pick=(const float*)d_in[5];
  const float* Pp[24];
  for (int i=0;i<24;i++) Pp[i]=(const float*)d_in[6+i];
  float* out=(float*)d_out;
  int cnt=(out_size-2)/256 - KN;
  if (cnt<0) cnt=0;

  char* w=(char*)d_ws;
  size_t off=0;
  auto carve=[&](size_t bytes)->char*{ off=(off+255)&~(size_t)255; char* p=w+off; off+=bytes; return p; };
  int*    counters=(int*)   carve(64);
  double* acc     =(double*)carve(64);
  float*  pr      =(float*) carve((size_t)KN*4);
  int*    choose  =(int*)   carve((size_t)KN*4);
  int*    excl    =(int*)   carve((size_t)KN*4);
  int*    iu      =(int*)   carve((size_t)KN*4);
  float*  p_ia    =(float*) carve((size_t)KN*4);
  int*    vc      =(int*)   carve((size_t)KN*4);
  int*    keep    =(int*)   carve((size_t)KN*4);
  int*    deg     =(int*)   carve((size_t)KN*4);
  int*    fill    =(int*)   carve((size_t)KN*4);
  int*    boff    =(int*)   carve((size_t)(KN+1)*4);
  int*    nodeseg =(int*)   carve((size_t)KN*4);
  int*    parA    =(int*)   carve((size_t)2*KM*4);
  int*    keyA    =(int*)   carve((size_t)2*KM*4);
  int*    ekA     =(int*)   carve((size_t)2*KM*4);
  int*    parS    =(int*)   carve((size_t)2*KM*4);
  int*    nbS     =(int*)   carve((size_t)2*KM*4);
  int*    ekS     =(int*)   carve((size_t)2*KM*4);
  float*  scores  =(float*) carve((size_t)2*KM*4);
  float*  yagg_f  =(float*) carve((size_t)KN*256*4);
  ushort* yagg_bf =(ushort*)carve((size_t)KN*256*2);
  float*  y1_f    =(float*) carve((size_t)KN*256*4);
  float*  y2_f    =(float*) carve((size_t)KN*256*4);
  ushort* x_bf    =(ushort*)carve((size_t)KN*512*2);
  ushort* x_lo    =(ushort*)carve((size_t)KN*512*2);
  ushort* W1t     =(ushort*)carve((size_t)832*128*2);
  double* w1d     =(double*)carve((size_t)512*256*8);
  ushort* W1yt    =(ushort*)carve((size_t)128*384*2);
  ushort* W2yt    =(ushort*)carve((size_t)256*128*2);
  ushort* Wrt_hi  =(ushort*)carve((size_t)256*512*2);
  ushort* Wrt_lo  =(ushort*)carve((size_t)256*512*2);
  float*  hy      =(float*) carve((size_t)KN*128*4);
  float*  hx      =(float*) carve((size_t)KN*128*4);
  (void)ws_size;(void)n_in;(void)in_sizes;

  const int RB=(KN+63)/64;    // 313 rmlp blocks
  const int HXB=KN/32;        // 625 hx blocks
  const int YB2=KN/32;        // 625 ymlp blocks (32 rows each)
  const int HB=KN/32;         // 625 hy blocks
  const int IAB=(cnt+15)/16;  // ia blocks
  const int SCB=(KN+31)/32;   // 625 scatter blocks
  const int NTB=(KN+255)/256; // 79 node_term blocks

  k_prep_all<<<(KN*512/8+255)/256,256,0,stream>>>(x,x_bf,x_lo,
      Pp[0],Wrt_hi,Wrt_lo,w1d, Pp[18],W1t, Pp[6],W1yt, Pp[10],W2yt,
      deg,fill,keep,counters,acc);
  k_mega1<<<RB+HXB+YB2,512,0,stream>>>(x,x_bf,x_lo,Wrt_hi,Wrt_lo,w1d,
      Pp[1],Pp[2],Pp[3],Pp[4],Pp[5],u_r,pr,choose,W1t,hx,
      W1yt,Pp[7],Pp[8],Pp[9],W2yt,Pp[11],y1_f,y2_f,yagg_f,yagg_bf,RB,HXB);
  k_scan_choose<<<1,1024,0,stream>>>(choose,excl,iu,counters);
  k_mega2<<<HB+IAB+SCB+NTB,256,0,stream>>>(yagg_f,yagg_bf,W1t,hy,iu,u_ia,
      Pp[12],Pp[13],Pp[14],Pp[15],Pp[16],Pp[17],p_ia,vc,keep,acc,
      y1_f,y2_f,choose,excl,out,pr,cnt,HB,IAB,SCB);
  k_count<<<(KM+255)/256,256,0,stream>>>(ei,keep,deg);
  k_scan_deg<<<1,1024,0,stream>>>(deg,boff,nodeseg,counters);
  k_fill<<<(KM+255)/256,256,0,stream>>>(ei,keep,boff,fill,parA,keyA,ekA);
  k_rank<<<(2*KM+255)/256,256,0,stream>>>(parA,keyA,ekA,boff,counters,parS,nbS,ekS);
  k_cscore_v6<<<2560,256,0,stream>>>(ea,hy,hx,parS,nbS,ekS,counters,W1t,Pp[19],Pp[20],Pp[21],Pp[22],Pp[23],scores);
  k_segment<<<(KN+255)/256,256,0,stream>>>(scores,boff,nodeseg,counters,u_pick,acc);
  k_final<<<1,64,0,stream>>>(acc,out,cnt);
}

// Round 13
// 405.808 us; speedup vs baseline: 1.0423x; 1.0423x over previous
//
#include <hip/hip_runtime.h>
#include <math.h>

#define KN 20000
#define KM 320000

typedef __attribute__((ext_vector_type(8))) short bf16x8;
typedef __attribute__((ext_vector_type(4))) float f32x4;

__device__ __forceinline__ ushort f2bf(float f){
  union{float f; unsigned u;} a; a.f=f;
  unsigned r = a.u + 0x7FFFu + ((a.u>>16)&1u);
  return (ushort)(r>>16);
}
__device__ __forceinline__ float bf2f(ushort u){
  union{unsigned u; float f;} a; a.u=((unsigned)u)<<16; return a.f;
}

// ---------------- helpers ----------------
__device__ __forceinline__ void blk_add2(double lp, double en, double* acc, double* sh){
#pragma unroll
  for (int o=32;o;o>>=1){ lp+=__shfl_xor(lp,o,64); en+=__shfl_xor(en,o,64); }
  int w=threadIdx.x>>6;
  if ((threadIdx.x&63)==0){ sh[2*w]=lp; sh[2*w+1]=en; }
  __syncthreads();
  if (threadIdx.x==0){
    double L=0,E=0; int nw=(blockDim.x+63)>>6;
    for (int i=0;i<nw;i++){L+=sh[2*i];E+=sh[2*i+1];}
    atomicAdd(&acc[0],L); atomicAdd(&acc[1],E);
  }
  __syncthreads();
}

// ---------------- consolidated prep: init + weight preps + x hi/lo split ----------------
__global__ __launch_bounds__(256) void k_prep_all(
    const float* __restrict__ x, ushort* __restrict__ x_hi, ushort* __restrict__ x_lo,
    const float* __restrict__ Wr1, ushort* __restrict__ Wrt_hi, ushort* __restrict__ Wrt_lo,
    double* __restrict__ w1d,
    const float* __restrict__ Wc1, ushort* __restrict__ W1t,
    const float* __restrict__ Wy1, ushort* __restrict__ W1yt,
    const float* __restrict__ Wy2, ushort* __restrict__ W2yt,
    int* __restrict__ deg,int* __restrict__ fill,int* __restrict__ keep,
    int* __restrict__ counters,double* __restrict__ acc){
  int i=blockIdx.x*256+threadIdx.x;
  if (i<KN*512/8){
    const float* s=x+(size_t)i*8;
    union{ushort u[8]; uint4 v;} oh, ol;
#pragma unroll
    for (int j=0;j<8;j++){
      float v=s[j];
      ushort h=f2bf(v);
      oh.u[j]=h;
      ol.u[j]=f2bf(v-bf2f(h));
    }
    *(uint4*)(x_hi+(size_t)i*8)=oh.v;
    *(uint4*)(x_lo+(size_t)i*8)=ol.v;
  }
  if (i<512*256){
    w1d[i]=(double)Wr1[i];
    int n=i&255, k=i>>8;
    float wv=Wr1[(size_t)k*256+n];
    ushort h=f2bf(wv);
    int kt=k>>5, kc=(k>>3)&3, j=k&7;
    size_t dst=(((size_t)kt*1024)+(size_t)kc*256+(size_t)n)*8+j;
    Wrt_hi[dst]=h;
    Wrt_lo[dst]=f2bf(wv-bf2f(h));
  }
  if (i<832*128){
    int n=i&127, k=i>>7;
    W1t[(size_t)n*832+k]=f2bf(Wc1[(size_t)k*128+n]);
  }
  if (i<384*128){
    int n=i&127, k=i>>7;
    W1yt[(size_t)n*384+k]=f2bf(Wy1[(size_t)k*128+n]);
  }
  if (i<128*256){
    int n=i&255, k=i>>8;
    W2yt[(size_t)n*128+k]=f2bf(Wy2[(size_t)k*256+n]);
  }
  if (i<KN){ deg[i]=0; fill[i]=0; keep[i]=0; }
  if (i<8) counters[i]=0;
  if (i<2) acc[i]=0.0;
}

// ---------------- mega1: rmlp + hx GEMM + ymlp-compute (choose-independent) ----------------
// R10 configuration (best measured: 407 us total). Contiguous type ranges; staged hi+lo dbuf.
// Placement-interleave (R12) and LDS-cut/L2-lo (R11) both regressed -> locked to this form.
#define RFLAG_TAU 3e-4f
#define YEXTP 261
__global__ __launch_bounds__(512) void k_mega1(const float* __restrict__ x,
    const ushort* __restrict__ x_hi,const ushort* __restrict__ x_lo,
    const ushort* __restrict__ Wrt_hi,const ushort* __restrict__ Wrt_lo,
    const double* __restrict__ w1d,
    const float* __restrict__ b1,const float* __restrict__ g1,
    const float* __restrict__ bt1,const float* __restrict__ W2,const float* __restrict__ b2,
    const float* __restrict__ u_r, float* __restrict__ pr, int* __restrict__ choose,
    const ushort* __restrict__ W1t, float* __restrict__ hxP,
    const ushort* __restrict__ W1yt,const float* __restrict__ b1y,const float* __restrict__ g1y,
    const float* __restrict__ bt1y,const ushort* __restrict__ W2yt,const float* __restrict__ b2y,
    float* __restrict__ y1_f,float* __restrict__ y2_f,
    float* __restrict__ yagg_f,ushort* __restrict__ yagg_bf,
    int RB,int HXB){
  __shared__ __align__(16) ushort Bl[2][2][8192];   // 64 KB (rmlp dbuf; ymlp aliases)
  __shared__ float psum[64][2], pvar[64][2], pdot[64][2];
  __shared__ int flagsh[64];
  __shared__ double dsh[256];
  int t=threadIdx.x;
  int w=t>>6, l=t&63;
  int lr=l&15, lk=l>>4;
  if ((int)blockIdx.x>=RB+HXB){
    // ---- ymlp-compute: 2 groups of 16 rows ----
    int b=blockIdx.x-RB-HXB;
    int sub=t>>8, tt=t&255;
    char* gbase=(char*)Bl + sub*25600;
    float*  hf  =(float*)gbase;
    float*  yext=(float*)gbase;
    ushort* hb  =(ushort*)(gbase+16896);
    int wy=tt>>6, ly=tt&63;
    int lry=ly&15, lky=ly>>4;
    int md=wy&1, kh=wy>>1;
    int row0=(b*2+sub)*16;
    const ushort* xr=x_hi+(size_t)(row0+lry)*512;
    f32x4 acc1[8];
#pragma unroll
    for (int c=0;c<8;c++) acc1[c]=(f32x4){0,0,0,0};
#pragma unroll
    for (int kt=0;kt<6;kt++){
      int k0=kh*192+kt*32+lky*8;
      int ks=(md && k0>=256)? k0+128 : k0;
      bf16x8 a=*(const bf16x8*)(xr+ks);
#pragma unroll
      for (int c=0;c<8;c++){
        bf16x8 b_=*(const bf16x8*)(W1yt+(size_t)(c*16+lry)*384+k0);
        acc1[c]=__builtin_amdgcn_mfma_f32_16x16x32_bf16(a,b_,acc1[c],0,0,0);
      }
    }
    if (kh==0){
#pragma unroll
      for (int i=0;i<4;i++){
        int row=lky*4+i;
#pragma unroll
        for (int c=0;c<8;c++) hf[((size_t)md*16+row)*132+c*16+lry]=acc1[c][i];
      }
    }
    __syncthreads();   // B1
    if (kh==1){
      float b1v[8],g1v[8],btv[8];
#pragma unroll
      for (int c=0;c<8;c++){ int col=c*16+lry; b1v[c]=b1y[col]; g1v[c]=g1y[col]; btv[c]=bt1y[col]; }
#pragma unroll
      for (int i=0;i<4;i++){
        int row=lky*4+i;
        float hv[8]; float s=0.f;
#pragma unroll
        for (int c=0;c<8;c++){ hv[c]=acc1[c][i]+hf[((size_t)md*16+row)*132+c*16+lry]+b1v[c]; s+=hv[c]; }
#pragma unroll
        for (int o=8;o;o>>=1) s+=__shfl_xor(s,o,64);
        float mu=s*(1.0f/128.0f);
        float v=0.f;
#pragma unroll
        for (int c=0;c<8;c++){ float d=hv[c]-mu; v+=d*d; }
#pragma unroll
        for (int o=8;o;o>>=1) v+=__shfl_xor(v,o,64);
        float rs=1.0f/sqrtf(v*(1.0f/128.0f)+1e-5f);
        ushort* hrow=hb+((size_t)md*16+row)*136;
#pragma unroll
        for (int c=0;c<8;c++){
          float hn=(hv[c]-mu)*rs*g1v[c]+btv[c];
          hn=hn>=0.f?hn:0.05f*hn;
          hrow[c*16+lry]=f2bf(hn);
        }
      }
    }
    __syncthreads();   // B2
    f32x4 acc2[8];
#pragma unroll
    for (int c=0;c<8;c++) acc2[c]=(f32x4){0,0,0,0};
    const ushort* ha=hb+((size_t)md*16+lry)*136;
#pragma unroll
    for (int kt=0;kt<4;kt++){
      bf16x8 a=*(const bf16x8*)(ha+kt*32+lky*8);
#pragma unroll
      for (int c=0;c<8;c++){
        bf16x8 b_=*(const bf16x8*)(W2yt+(size_t)(kh*128+c*16+lry)*128+kt*32+lky*8);
        acc2[c]=__builtin_amdgcn_mfma_f32_16x16x32_bf16(a,b_,acc2[c],0,0,0);
      }
    }
    float b2v[8];
#pragma unroll
    for (int c=0;c<8;c++) b2v[c]=b2y[kh*128+c*16+lry];
    if (md==0){
#pragma unroll
      for (int i=0;i<4;i++){
        int row=lky*4+i;
#pragma unroll
        for (int c=0;c<8;c++) yext[(size_t)row*YEXTP+kh*128+c*16+lry]=acc2[c][i]+b2v[c];
      }
    }
    __syncthreads();   // B3
    if (md==0){
#pragma unroll
      for (int i=0;i<4;i++){
        int row=lky*4+i, n=row0+row;
        float* orow=y1_f+(size_t)n*256+kh*128;
#pragma unroll
        for (int c=0;c<8;c++) orow[c*16+lry]=acc2[c][i]+b2v[c];
      }
    } else {
#pragma unroll
      for (int i=0;i<4;i++){
        int row=lky*4+i, n=row0+row;
        size_t base=(size_t)n*256+kh*128;
#pragma unroll
        for (int c=0;c<8;c++){
          int colk=c*16+lry;
          float v2=acc2[c][i]+b2v[c];
          float v1=yext[(size_t)row*YEXTP+kh*128+colk];
          float ga=v1+v2; ga=ga>=0.f?ga:0.05f*ga;
          yagg_f[base+colk]=ga;
          yagg_bf[base+colk]=f2bf(ga);
          y2_f[base+colk]=v2;
        }
      }
    }
    return;
  }
  if ((int)blockIdx.x>=RB){
    // ---- hx: rows b2*32 + (w>>2)*16, cols (w&3)*32 .. +31 ----
    int b2=blockIdx.x-RB;
    int rh=w>>2, cw=w&3;
    int row0=b2*32+rh*16;
    const ushort* ar=x_hi+(size_t)(row0+lr)*512;
    f32x4 acc3[2];
#pragma unroll
    for (int c=0;c<2;c++) acc3[c]=(f32x4){0,0,0,0};
#pragma unroll
    for (int kt=0;kt<16;kt++){
      bf16x8 a=*(const bf16x8*)(ar+320+kt*32+lk*8);
#pragma unroll
      for (int c=0;c<2;c++){
        bf16x8 b=*(const bf16x8*)(W1t+(size_t)(cw*32+c*16+lr)*832+320+kt*32+lk*8);
        acc3[c]=__builtin_amdgcn_mfma_f32_16x16x32_bf16(a,b,acc3[c],0,0,0);
      }
    }
#pragma unroll
    for (int i=0;i<4;i++){
      int n=row0+lk*4+i;
      float2 v; v.x=acc3[0][i]; v.y=acc3[1][i];
      *(float2*)(hxP+(size_t)n*128+lr*8+cw*2)=v;
    }
    return;
  }
  int rg=w>>1, ch=w&1;
  int row0=blockIdx.x*64;
  if (t<64) flagsh[t]=0;
  int q0=t*2, q1=t*2+1;
  f32x4 acc[8];
#pragma unroll
  for (int c=0;c<8;c++) acc[c]=(f32x4){0,0,0,0};
  int rowA=row0+rg*16+lr; if (rowA>=KN) rowA=KN-1;
  const ushort* ah=x_hi+(size_t)rowA*512;
  const ushort* al=x_lo+(size_t)rowA*512;
  bf16x8 nh0=*(const bf16x8*)(Wrt_hi+q0*8);
  bf16x8 nh1=*(const bf16x8*)(Wrt_hi+q1*8);
  bf16x8 nl0=*(const bf16x8*)(Wrt_lo+q0*8);
  bf16x8 nl1=*(const bf16x8*)(Wrt_lo+q1*8);
  *(bf16x8*)&Bl[0][0][q0*8]=nh0; *(bf16x8*)&Bl[0][0][q1*8]=nh1;
  *(bf16x8*)&Bl[0][1][q0*8]=nl0; *(bf16x8*)&Bl[0][1][q1*8]=nl1;
  nh0=*(const bf16x8*)(Wrt_hi+8192+q0*8);
  nh1=*(const bf16x8*)(Wrt_hi+8192+q1*8);
  nl0=*(const bf16x8*)(Wrt_lo+8192+q0*8);
  nl1=*(const bf16x8*)(Wrt_lo+8192+q1*8);
  bf16x8 a_h0=*(const bf16x8*)(ah+0*32+lk*8), a_l0=*(const bf16x8*)(al+0*32+lk*8);
  bf16x8 a_h1=*(const bf16x8*)(ah+1*32+lk*8), a_l1=*(const bf16x8*)(al+1*32+lk*8);
  bf16x8 a_h2=*(const bf16x8*)(ah+2*32+lk*8), a_l2=*(const bf16x8*)(al+2*32+lk*8);
  bf16x8 a_h3=*(const bf16x8*)(ah+3*32+lk*8), a_l3=*(const bf16x8*)(al+3*32+lk*8);
  __syncthreads();
#define RBODY(KT,AH,AL) { \
    const int cur_=(KT)&1, nxt_=cur_^1; \
    if ((KT)<15){ \
      *(bf16x8*)&Bl[nxt_][0][q0*8]=nh0; *(bf16x8*)&Bl[nxt_][0][q1*8]=nh1; \
      *(bf16x8*)&Bl[nxt_][1][q0*8]=nl0; *(bf16x8*)&Bl[nxt_][1][q1*8]=nl1; \
      if ((KT)<14){ \
        size_t so_=(size_t)((KT)+2)*8192; \
        nh0=*(const bf16x8*)(Wrt_hi+so_+q0*8); nh1=*(const bf16x8*)(Wrt_hi+so_+q1*8); \
        nl0=*(const bf16x8*)(Wrt_lo+so_+q0*8); nl1=*(const bf16x8*)(Wrt_lo+so_+q1*8); \
      } \
    } \
    bf16x8 uh_=AH, ul_=AL; \
    if ((KT)<12){ \
      int ko_=((KT)+4)*32+lk*8; \
      AH=*(const bf16x8*)(ah+ko_); \
      AL=*(const bf16x8*)(al+ko_); \
    } \
    _Pragma("unroll") \
    for (int c=0;c<8;c++){ \
      int col_=ch*128+c*16+lr; \
      bf16x8 vh_=*(const bf16x8*)&Bl[cur_][0][((lk<<8)+col_)*8]; \
      bf16x8 vl_=*(const bf16x8*)&Bl[cur_][1][((lk<<8)+col_)*8]; \
      acc[c]=__builtin_amdgcn_mfma_f32_16x16x32_bf16(uh_,vh_,acc[c],0,0,0); \
      acc[c]=__builtin_amdgcn_mfma_f32_16x16x32_bf16(uh_,vl_,acc[c],0,0,0); \
      acc[c]=__builtin_amdgcn_mfma_f32_16x16x32_bf16(ul_,vh_,acc[c],0,0,0); \
    } \
    __syncthreads(); \
  }
  RBODY(0,a_h0,a_l0)  RBODY(1,a_h1,a_l1)  RBODY(2,a_h2,a_l2)  RBODY(3,a_h3,a_l3)
  RBODY(4,a_h0,a_l0)  RBODY(5,a_h1,a_l1)  RBODY(6,a_h2,a_l2)  RBODY(7,a_h3,a_l3)
  RBODY(8,a_h0,a_l0)  RBODY(9,a_h1,a_l1)  RBODY(10,a_h2,a_l2) RBODY(11,a_h3,a_l3)
  RBODY(12,a_h0,a_l0) RBODY(13,a_h1,a_l1) RBODY(14,a_h2,a_l2) RBODY(15,a_h3,a_l3)
#undef RBODY
  float b1v[8],g1v[8],btv[8],w2v[8];
#pragma unroll
  for (int c=0;c<8;c++){
    int col=ch*128+c*16+lr;
    b1v[c]=b1[col]; g1v[c]=g1[col]; btv[c]=bt1[col]; w2v[c]=W2[col];
  }
  float hv[4][8];
#pragma unroll
  for (int i=0;i<4;i++){
    float s=0.f;
#pragma unroll
    for (int c=0;c<8;c++){ hv[i][c]=acc[c][i]+b1v[c]; s+=hv[i][c]; }
#pragma unroll
    for (int o=8;o;o>>=1) s+=__shfl_xor(s,o,64);
    if (lr==0) psum[rg*16+lk*4+i][ch]=s;
  }
  __syncthreads();
  float mu_[4];
#pragma unroll
  for (int i=0;i<4;i++){
    int r=rg*16+lk*4+i;
    mu_[i]=(psum[r][0]+psum[r][1])*(1.0f/256.0f);
    float v=0.f;
#pragma unroll
    for (int c=0;c<8;c++){ float d=hv[i][c]-mu_[i]; v+=d*d; }
#pragma unroll
    for (int o=8;o;o>>=1) v+=__shfl_xor(v,o,64);
    if (lr==0) pvar[r][ch]=v;
  }
  __syncthreads();
#pragma unroll
  for (int i=0;i<4;i++){
    int r=rg*16+lk*4+i;
    float rs=1.0f/sqrtf((pvar[r][0]+pvar[r][1])*(1.0f/256.0f)+1e-5f);
    float dot=0.f;
#pragma unroll
    for (int c=0;c<8;c++){
      float hn=(hv[i][c]-mu_[i])*rs*g1v[c]+btv[c];
      hn=hn>=0.f?hn:0.05f*hn;
      dot=fmaf(hn,w2v[c],dot);
    }
#pragma unroll
    for (int o=8;o;o>>=1) dot+=__shfl_xor(dot,o,64);
    if (lr==0) pdot[r][ch]=dot;
  }
  __syncthreads();
  if (t<64){
    int n=row0+t;
    if (n<KN){
      float o2=pdot[t][0]+pdot[t][1]+b2[0];
      float pf=1.0f/(1.0f+expf(-o2));
      float u=u_r[n];
      pr[n]=pf;
      choose[n]=(u<pf)?1:0;
      if (fabsf(pf-u)<RFLAG_TAU) flagsh[t]=1;
    }
  }
  __syncthreads();
  for (int r=0;r<64;r++){
    if (!flagsh[r]) continue;
    int n=row0+r;
    if (t<256){
      double ha=(double)b1[t];
      const float* xr=x+(size_t)n*512;
      for (int k=0;k<512;k++) ha=fma((double)xr[k],w1d[(size_t)k*256+t],ha);
      dsh[t]=ha;
    }
    __syncthreads();
    if (t<64){
      double s=0;
      for (int j=t;j<256;j+=64) s+=dsh[j];
#pragma unroll
      for (int o=32;o;o>>=1) s+=__shfl_xor(s,o,64);
      double mu=s*(1.0/256.0);
      double v=0;
      for (int j=t;j<256;j+=64){ double d=dsh[j]-mu; v+=d*d; }
#pragma unroll
      for (int o=32;o;o>>=1) v+=__shfl_xor(v,o,64);
      double rs=1.0/sqrt(v*(1.0/256.0)+1e-5);
      double dot=0;
      for (int j=t;j<256;j+=64){
        double hn=(dsh[j]-mu)*rs*(double)g1[j]+(double)bt1[j];
        hn = hn>=0.0? hn : 0.05*hn;
        dot=fma(hn,(double)W2[j],dot);
      }
#pragma unroll
      for (int o=32;o;o>>=1) dot+=__shfl_xor(dot,o,64);
      if (t==0){
        double p=1.0/(1.0+exp(-(dot+(double)b2[0])));
        float pf=(float)p;
        pr[n]=pf;
        choose[n]=(u_r[n]<pf)?1:0;
      }
    }
    __syncthreads();
  }
}

// ---------------- single-block scan (wave-shuffle) ----------------
__global__ __launch_bounds__(1024) void k_scan_choose(const int* __restrict__ choose,int* __restrict__ excl,
                                                      int* __restrict__ iu,int* __restrict__ counters){
  __shared__ int wsum[16], woff[16];
  const int CH=(KN+1023)/1024;
  int t=threadIdx.x, lane=t&63, wid=t>>6;
  int base=t*CH;
  int s=0;
  for (int i=0;i<CH;i++){int idx=base+i; if (idx<KN) s+=choose[idx];}
  int inc=s;
  for (int o=1;o<64;o<<=1){ int v=__shfl_up(inc,o,64); if (lane>=o) inc+=v; }
  if (lane==63) wsum[wid]=inc;
  __syncthreads();
  if (t==0){ int r=0; for (int i=0;i<16;i++){ woff[i]=r; r+=wsum[i]; } counters[2]=r; }
  __syncthreads();
  int ex=woff[wid]+inc-s;
  for (int i=0;i<CH;i++){
    int idx=base+i;
    if (idx<KN){ int c=choose[idx]; excl[idx]=ex; if (c) iu[ex]=idx; ex+=c; }
  }
}

// ---------------- mega2: hy GEMM + ia MLP + y1/y2 scatter + node_term ----------------
__global__ __launch_bounds__(256) void k_mega2(const float* __restrict__ yagg_f,
    const ushort* __restrict__ yagg_bf,const ushort* __restrict__ W1t,float* __restrict__ hyP,
    const int* __restrict__ iu,const float* __restrict__ u_ia,
    const float* __restrict__ W1,const float* __restrict__ b1,const float* __restrict__ g1,
    const float* __restrict__ bt1,const float* __restrict__ W2,const float* __restrict__ b2,
    float* __restrict__ p_ia,int* __restrict__ vc,int* __restrict__ keep,double* __restrict__ acc,
    const float* __restrict__ y1_f,const float* __restrict__ y2_f,
    const int* __restrict__ choose,const int* __restrict__ excl,
    float* __restrict__ out,const float* __restrict__ pr,
    int cnt,int HB,int IAB,int SCB){
  __shared__ float insh[16][256];
  __shared__ float hsh[16][128];
  __shared__ double sh[8];
  int t=threadIdx.x;
  int w=t>>6, l=t&63;
  int lr=l&15, lk=l>>4;
  if ((int)blockIdx.x<HB){
    int rh=w>>1, cq=w&1;
    int row0=blockIdx.x*32+rh*16;
    const ushort* ar=yagg_bf+(size_t)(row0+lr)*256+lk*8;
    f32x4 acc4[4];
#pragma unroll
    for (int c=0;c<4;c++) acc4[c]=(f32x4){0,0,0,0};
#pragma unroll
    for (int kt=0;kt<8;kt++){
      bf16x8 a=*(const bf16x8*)(ar+kt*32);
#pragma unroll
      for (int c=0;c<4;c++){
        bf16x8 b=*(const bf16x8*)(W1t+(size_t)(cq*64+c*16+lr)*832+kt*32+lk*8);
        acc4[c]=__builtin_amdgcn_mfma_f32_16x16x32_bf16(a,b,acc4[c],0,0,0);
      }
    }
#pragma unroll
    for (int i=0;i<4;i++){
      int n=row0+lk*4+i;
      float4 v; v.x=acc4[0][i]; v.y=acc4[1][i]; v.z=acc4[2][i]; v.w=acc4[3][i];
      *(float4*)(hyP+(size_t)n*128+lr*8+cq*4)=v;
    }
    return;
  }
  if ((int)blockIdx.x<HB+IAB){
    int row0=(blockIdx.x-HB)*16;
    for (int i=t;i<16*256;i+=256){
      int r=i>>8,k=i&255;
      int row=row0+r;
      if (row<cnt){
        unsigned n=(unsigned)iu[row];
        if (n<KN) insh[r][k]=yagg_f[(size_t)n*256+k];
        else insh[r][k]=0.f;
      }
    }
    __syncthreads();
    int h=t>>7, tt=t&127;
    float accv[8]; float bb=b1[tt];
#pragma unroll
    for (int r=0;r<8;r++) accv[r]=bb;
    for (int k=0;k<256;k+=4){
      float w0=W1[(k+0)*128+tt],w1=W1[(k+1)*128+tt],w2=W1[(k+2)*128+tt],w3=W1[(k+3)*128+tt];
#pragma unroll
      for (int r=0;r<8;r++){
        float4 f=*(const float4*)&insh[h*8+r][k];
        accv[r]=fmaf(f.x,w0,accv[r]); accv[r]=fmaf(f.y,w1,accv[r]); accv[r]=fmaf(f.z,w2,accv[r]); accv[r]=fmaf(f.w,w3,accv[r]);
      }
    }
#pragma unroll
    for (int r=0;r<8;r++) hsh[h*8+r][tt]=accv[r];
    __syncthreads();
    int g=t>>4, tl=t&15;
    float hv[8];
#pragma unroll
    for (int j=0;j<8;j++) hv[j]=hsh[g][tl+16*j];
    float s=0;
#pragma unroll
    for (int j=0;j<8;j++) s+=hv[j];
#pragma unroll
    for (int o=8;o;o>>=1) s+=__shfl_xor(s,o,64);
    float mu=s*(1.0f/128.0f);
    float v=0;
#pragma unroll
    for (int j=0;j<8;j++){float d=hv[j]-mu; v+=d*d;}
#pragma unroll
    for (int o=8;o;o>>=1) v+=__shfl_xor(v,o,64);
    float rs=1.0f/sqrtf(v*(1.0f/128.0f)+1e-5f);
    float dot=0;
#pragma unroll
    for (int j=0;j<8;j++){
      int idx=tl+16*j;
      float hn=(hv[j]-mu)*rs*g1[idx]+bt1[idx];
      hn=hn>=0.f?hn:0.05f*hn;
      dot=fmaf(hn,W2[idx],dot);
    }
#pragma unroll
    for (int o=8;o;o>>=1) dot+=__shfl_xor(dot,o,64);
    double lp=0,en=0;
    if (tl==0){
      int row=row0+g;
      if (row<cnt){
        unsigned n=(unsigned)iu[row];
        if (n<KN){
          float o=dot+b2[0];
          double p=1.0/(1.0+exp(-(double)o));
          float pf=(float)p;
          p_ia[row]=pf;
          int vv=(u_ia[n]<pf)?1:0;
          vc[row]=vv;
          if(!vv) keep[n]=1;
          lp = vv? log((double)pf+1e-9) : log(1.0-(double)pf+1e-9);
          double ps=fmin(fmax((double)pf,1e-9),1.0-1e-9);
          en = -(ps*log(ps)+(1.0-ps)*log(1.0-ps));
        }
      }
    }
    blk_add2(lp,en,acc,sh);
    return;
  }
  if ((int)blockIdx.x<HB+IAB+SCB){
    int b=blockIdx.x-HB-IAB;
    int r0=b*32;
    for (int r=0;r<32;r++){
      int n=r0+r;
      if (n>=KN) break;
      int cch=choose[n], ex=excl[n];
      int r1 = cch? (KN-cnt)+ex : n-ex;
      if (r1>=0 && r1<KN+cnt) out[(size_t)r1*256+t]=y1_f[(size_t)n*256+t];
      if (cch){ int r2=KN+ex; if (r2<KN+cnt) out[(size_t)r2*256+t]=y2_f[(size_t)n*256+t]; }
    }
    return;
  }
  {
    int i=(blockIdx.x-HB-IAB-SCB)*256+t;
    double lp=0,en=0;
    if (i<KN){
      double p=(double)pr[i];
      lp = choose[i]? log(p+1e-9) : log(1.0-p+1e-9);
      double ps=fmin(fmax(p,1e-9),1.0-1e-9);
      en = -(ps*log(ps)+(1.0-ps)*log(1.0-ps));
    }
    blk_add2(lp,en,acc,(double*)insh);
  }
}

// ---------------- adjacency build ----------------
__global__ void k_count(const int* __restrict__ ei,const int* __restrict__ keep,int* __restrict__ deg){
  int e=blockIdx.x*256+threadIdx.x;
  if (e<KM){
    int s=ei[e], d=ei[KM+e];
    if (keep[s]) atomicAdd(&deg[s],1);
    if (keep[d]) atomicAdd(&deg[d],1);
  }
}

__global__ __launch_bounds__(1024) void k_scan_deg(const int* __restrict__ deg,int* __restrict__ boff,
                                                   int* __restrict__ nodeseg,int* __restrict__ counters){
  __shared__ int wsum[16], woff[16];
  const int CH=(KN+1023)/1024;
  int t=threadIdx.x, lane=t&63, wid=t>>6;
  int base=t*CH;
  int s=0, sc=0;
  for (int i=0;i<CH;i++){int idx=base+i; if(idx<KN){ int d=deg[idx]; s+=d; sc+=(d>0)?1:0; }}
  int inc=s;
  for (int o=1;o<64;o<<=1){ int v=__shfl_up(inc,o,64); if (lane>=o) inc+=v; }
  if (lane==63) wsum[wid]=inc;
  __syncthreads();
  if (t==0){ int r=0; for (int i=0;i<16;i++){ woff[i]=r; r+=wsum[i]; } boff[KN]=r; counters[0]=r; }
  __syncthreads();
  int ex=woff[wid]+inc-s;
  for (int i=0;i<CH;i++){int idx=base+i; if(idx<KN){ boff[idx]=ex; ex+=deg[idx]; }}
  __syncthreads();
  int inc2=sc;
  for (int o=1;o<64;o<<=1){ int v=__shfl_up(inc2,o,64); if (lane>=o) inc2+=v; }
  if (lane==63) wsum[wid]=inc2;
  __syncthreads();
  if (t==0){ int r=0; for (int i=0;i<16;i++){ woff[i]=r; r+=wsum[i]; } counters[1]=r; }
  __syncthreads();
  int ex2=woff[wid]+inc2-sc;
  for (int i=0;i<CH;i++){int idx=base+i; if(idx<KN && deg[idx]>0){ nodeseg[ex2]=idx; ex2++; }}
}

// key = nb*2 + half -> replicates stable lexsort tie-break
__global__ void k_fill(const int* __restrict__ ei,const int* __restrict__ keep,const int* __restrict__ boff,
                       int* __restrict__ fill,int* __restrict__ parA,int* __restrict__ keyA,int* __restrict__ ekA){
  int e=blockIdx.x*256+threadIdx.x;
  if (e<KM){
    int s=ei[e], d=ei[KM+e];
    if (keep[s]){ int pos=boff[s]+atomicAdd(&fill[s],1); parA[pos]=s; keyA[pos]=d*2;   ekA[pos]=e; }
    if (keep[d]){ int pos=boff[d]+atomicAdd(&fill[d],1); parA[pos]=d; keyA[pos]=s*2+1; ekA[pos]=e; }
  }
}

__global__ void k_rank(const int* __restrict__ parA,const int* __restrict__ keyA,const int* __restrict__ ekA,
                       const int* __restrict__ boff,const int* __restrict__ counters,
                       int* __restrict__ parS,int* __restrict__ nbS,int* __restrict__ ekS){
  int i=blockIdx.x*256+threadIdx.x;
  int Pn=counters[0];
  if (i<Pn){
    int par=parA[i], key=keyA[i];
    int lo=boff[par], hi=boff[par+1];
    int rank=0;
    for (int j=lo;j<hi;j++) rank += (keyA[j]<key)?1:0;
    int pos=lo+rank;
    parS[pos]=par; nbS[pos]=key>>1; ekS[pos]=ekA[i];
  }
}

// ---------------- c scores v6: no LDS, no barriers; ea converted inline ----------------
__global__ __launch_bounds__(256) void k_cscore_v6(
    const float* __restrict__ ea,const float* __restrict__ hyP,const float* __restrict__ hxP,
    const int* __restrict__ parS,const int* __restrict__ nbS,const int* __restrict__ ekS,
    const int* __restrict__ counters,
    const ushort* __restrict__ W1t,const float* __restrict__ b1,const float* __restrict__ g1,
    const float* __restrict__ bt1,const float* __restrict__ W2,const float* __restrict__ b2,
    float* __restrict__ scores){
  int Pn=counters[0];
  if (Pn<=0) return;
  int t=threadIdx.x;
  int w=t>>6, l=t&63;
  int lr=l&15, lk=l>>4;
  float b2s=b2[0];
  float b1v[8],g1v[8],btv[8],w2v[8];
#pragma unroll
  for (int c=0;c<8;c++){
    int col=c*16+lr;
    b1v[c]=b1[col]; g1v[c]=g1[col]; btv[c]=bt1[col]; w2v[c]=W2[col];
  }
  int ngrp=(Pn+63)>>6;
  for (int g=blockIdx.x; g<ngrp; g+=gridDim.x){
    int p0=g*64+w*16;
    float hs[4][8];
#pragma unroll
    for (int i=0;i<4;i++){
      int p=p0+lk*4+i; int pc=p<Pn?p:Pn-1;
      const float* hyp=hyP+(size_t)parS[pc]*128+lr*8;
      const float* hxp=hxP+(size_t)nbS[pc]*128+lr*8;
      float4 ya=*(const float4*)hyp, yb=*(const float4*)(hyp+4);
      float4 xa=*(const float4*)hxp, xb=*(const float4*)(hxp+4);
      hs[i][0]=ya.x+xa.x; hs[i][1]=ya.y+xa.y; hs[i][2]=ya.z+xa.z; hs[i][3]=ya.w+xa.w;
      hs[i][4]=yb.x+xb.x; hs[i][5]=yb.y+xb.y; hs[i][6]=yb.z+xb.z; hs[i][7]=yb.w+xb.w;
    }
    int pA=p0+lr; int ca=pA<Pn?pA:Pn-1;
    const float* eaA=ea+(size_t)ekS[ca]*64;
    f32x4 acc[8];
#pragma unroll
    for (int c=0;c<8;c++) acc[c]=(f32x4){0,0,0,0};
#pragma unroll
    for (int kt=0;kt<2;kt++){
      float4 fa=*(const float4*)(eaA+kt*32+lk*8);
      float4 fb=*(const float4*)(eaA+kt*32+lk*8+4);
      union{ushort u[8]; bf16x8 v;} A;
      A.u[0]=f2bf(fa.x); A.u[1]=f2bf(fa.y); A.u[2]=f2bf(fa.z); A.u[3]=f2bf(fa.w);
      A.u[4]=f2bf(fb.x); A.u[5]=f2bf(fb.y); A.u[6]=f2bf(fb.z); A.u[7]=f2bf(fb.w);
      bf16x8 a=A.v;
#pragma unroll
      for (int c=0;c<8;c++){
        bf16x8 b=*(const bf16x8*)(W1t+(size_t)(c*16+lr)*832+256+kt*32+lk*8);
        acc[c]=__builtin_amdgcn_mfma_f32_16x16x32_bf16(a,b,acc[c],0,0,0);
      }
    }
#pragma unroll
    for (int i=0;i<4;i++){
      float hv[8]; float s=0.f;
#pragma unroll
      for (int c=0;c<8;c++){ hv[c]=acc[c][i]+hs[i][c]+b1v[c]; s+=hv[c]; }
#pragma unroll
      for (int o=8;o;o>>=1) s+=__shfl_xor(s,o,64);
      float mu=s*(1.0f/128.0f);
      float v=0.f;
#pragma unroll
      for (int c=0;c<8;c++){ float d=hv[c]-mu; v+=d*d; }
#pragma unroll
      for (int o=8;o;o>>=1) v+=__shfl_xor(v,o,64);
      float rs=1.0f/sqrtf(v*(1.0f/128.0f)+1e-5f);
      float dot=0.f;
#pragma unroll
      for (int c=0;c<8;c++){
        float hn=(hv[c]-mu)*rs*g1v[c]+btv[c];
        hn=hn>=0.f?hn:0.05f*hn;
        dot=fmaf(hn,w2v[c],dot);
      }
#pragma unroll
      for (int o=8;o;o>>=1) dot+=__shfl_xor(dot,o,64);
      if (lr==0){
        int prow=p0+lk*4+i;
        if (prow<Pn) scores[prow]=dot+b2s;
      }
    }
  }
}

// ---------------- per-segment softmax, pick, logP/ent ----------------
__global__ __launch_bounds__(256) void k_segment(const float* __restrict__ scores,const int* __restrict__ boff,
    const int* __restrict__ nodeseg,const int* __restrict__ counters,const float* __restrict__ u_pick,
    double* __restrict__ acc){
  __shared__ double sh[8];
  int nseg=counters[1];
  int s=blockIdx.x*256+threadIdx.x;
  double lp=0,en=0;
  if (s<nseg){
    int n=nodeseg[s];
    int lo=boff[n],hi=boff[n+1];
    float mx=-1e30f;
    for (int p=lo;p<hi;p++) mx=fmaxf(mx,scores[p]);
    float den=0;
    for (int p=lo;p<hi;p++) den+=expf(scores[p]-mx);
    double u=(double)u_pick[n];
    double cum=0; float ppick=-1.f; float plast=0.f;
    for (int p=lo;p<hi;p++){
      float e=expf(scores[p]-mx);
      float prob=e/den;
      double pc=fmax((double)prob,1e-9);
      en -= pc*log(pc);
      plast=prob;
      if (ppick<0.f){ cum+=(double)prob; if (cum>u) ppick=prob; }
    }
    if (ppick<0.f) ppick=plast;
    lp=log(fmax((double)ppick,1e-9));
  }
  blk_add2(lp,en,acc,sh);
}

__global__ void k_final(const double* __restrict__ acc,float* __restrict__ out,int cnt){
  if (threadIdx.x==0 && blockIdx.x==0){
    size_t base=(size_t)(KN+cnt)*256;
    out[base]=(float)acc[0];
    out[base+1]=(float)acc[1];
  }
}

// ---------------- host ----------------
extern "C" void kernel_launch(void* const* d_in,const int* in_sizes,int n_in,
                              void* d_out,int out_size,void* d_ws,size_t ws_size,
                              hipStream_t stream){
  const float* x     =(const float*)d_in[0];
  const int*   ei    =(const int*)  d_in[1];
  const float* ea    =(const float*)d_in[2];
  const float* u_r   =(const float*)d_in[3];
  const float* u_ia  =(const float*)d_in[4];
  const float* u_pick=(const float*)d_in[5];
  const float* Pp[24];
  for (int i=0;i<24;i++) Pp[i]=(const float*)d_in[6+i];
  float* out=(float*)d_out;
  int cnt=(out_size-2)/256 - KN;
  if (cnt<0) cnt=0;

  char* w=(char*)d_ws;
  size_t off=0;
  auto carve=[&](size_t bytes)->char*{ off=(off+255)&~(size_t)255; char* p=w+off; off+=bytes; return p; };
  int*    counters=(int*)   carve(64);
  double* acc     =(double*)carve(64);
  float*  pr      =(float*) carve((size_t)KN*4);
  int*    choose  =(int*)   carve((size_t)KN*4);
  int*    excl    =(int*)   carve((size_t)KN*4);
  int*    iu      =(int*)   carve((size_t)KN*4);
  float*  p_ia    =(float*) carve((size_t)KN*4);
  int*    vc      =(int*)   carve((size_t)KN*4);
  int*    keep    =(int*)   carve((size_t)KN*4);
  int*    deg     =(int*)   carve((size_t)KN*4);
  int*    fill    =(int*)   carve((size_t)KN*4);
  int*    boff    =(int*)   carve((size_t)(KN+1)*4);
  int*    nodeseg =(int*)   carve((size_t)KN*4);
  int*    parA    =(int*)   carve((size_t)2*KM*4);
  int*    keyA    =(int*)   carve((size_t)2*KM*4);
  int*    ekA     =(int*)   carve((size_t)2*KM*4);
  int*    parS    =(int*)   carve((size_t)2*KM*4);
  int*    nbS     =(int*)   carve((size_t)2*KM*4);
  int*    ekS     =(int*)   carve((size_t)2*KM*4);
  float*  scores  =(float*) carve((size_t)2*KM*4);
  float*  yagg_f  =(float*) carve((size_t)KN*256*4);
  ushort* yagg_bf =(ushort*)carve((size_t)KN*256*2);
  float*  y1_f    =(float*) carve((size_t)KN*256*4);
  float*  y2_f    =(float*) carve((size_t)KN*256*4);
  ushort* x_bf    =(ushort*)carve((size_t)KN*512*2);
  ushort* x_lo    =(ushort*)carve((size_t)KN*512*2);
  ushort* W1t     =(ushort*)carve((size_t)832*128*2);
  double* w1d     =(double*)carve((size_t)512*256*8);
  ushort* W1yt    =(ushort*)carve((size_t)128*384*2);
  ushort* W2yt    =(ushort*)carve((size_t)256*128*2);
  ushort* Wrt_hi  =(ushort*)carve((size_t)256*512*2);
  ushort* Wrt_lo  =(ushort*)carve((size_t)256*512*2);
  float*  hy      =(float*) carve((size_t)KN*128*4);
  float*  hx      =(float*) carve((size_t)KN*128*4);
  (void)ws_size;(void)n_in;(void)in_sizes;

  const int RB=(KN+63)/64;    // 313 rmlp blocks
  const int HXB=KN/32;        // 625 hx blocks
  const int YB2=KN/32;        // 625 ymlp blocks (32 rows each)
  const int HB=KN/32;         // 625 hy blocks
  const int IAB=(cnt+15)/16;  // ia blocks
  const int SCB=(KN+31)/32;   // 625 scatter blocks
  const int NTB=(KN+255)/256; // 79 node_term blocks

  k_prep_all<<<(KN*512/8+255)/256,256,0,stream>>>(x,x_bf,x_lo,
      Pp[0],Wrt_hi,Wrt_lo,w1d, Pp[18],W1t, Pp[6],W1yt, Pp[10],W2yt,
      deg,fill,keep,counters,acc);
  k_mega1<<<RB+HXB+YB2,512,0,stream>>>(x,x_bf,x_lo,Wrt_hi,Wrt_lo,w1d,
      Pp[1],Pp[2],Pp[3],Pp[4],Pp[5],u_r,pr,choose,W1t,hx,
      W1yt,Pp[7],Pp[8],Pp[9],W2yt,Pp[11],y1_f,y2_f,yagg_f,yagg_bf,RB,HXB);
  k_scan_choose<<<1,1024,0,stream>>>(choose,excl,iu,counters);
  k_mega2<<<HB+IAB+SCB+NTB,256,0,stream>>>(yagg_f,yagg_bf,W1t,hy,iu,u_ia,
      Pp[12],Pp[13],Pp[14],Pp[15],Pp[16],Pp[17],p_ia,vc,keep,acc,
      y1_f,y2_f,choose,excl,out,pr,cnt,HB,IAB,SCB);
  k_count<<<(KM+255)/256,256,0,stream>>>(ei,keep,deg);
  k_scan_deg<<<1,1024,0,stream>>>(deg,boff,nodeseg,counters);
  k_fill<<<(KM+255)/256,256,0,stream>>>(ei,keep,boff,fill,parA,keyA,ekA);
  k_rank<<<(2*KM+255)/256,256,0,stream>>>(parA,keyA,ekA,boff,counters,parS,nbS,ekS);
  k_cscore_v6<<<2560,256,0,stream>>>(ea,hy,hx,parS,nbS,ekS,counters,W1t,Pp[19],Pp[20],Pp[21],Pp[22],Pp[23],scores);
  k_segment<<<(KN+255)/256,256,0,stream>>>(scores,boff,nodeseg,counters,u_pick,acc);
  k_final<<<1,64,0,stream>>>(acc,out,cnt);
}